// Round 1
// baseline (379.343 us; speedup 1.0000x reference)
//
#include <hip/hip_runtime.h>

#define IN_F 8192
#define OUT_F 8192
#define NB 16
#define NG 64                    // scale groups (group = 128 in-features)
#define KSPLIT 8
#define KRANGE (IN_F / KSPLIT)   // 1024 K per block
#define NSTEP (KRANGE / 32)      // 32 MFMA K-steps per block
#define GPB (KRANGE / 128)       // 8 scale groups per block

typedef __attribute__((ext_vector_type(8))) short bf16x8;
typedef __attribute__((ext_vector_type(4))) float f32x4;

// pack 2 floats -> 2 bf16 (round-half-away): 2 adds + 1 v_perm_b32
static __device__ __forceinline__ unsigned bfpack2(float a, float b) {
    unsigned ua = __float_as_uint(a) + 0x8000u;
    unsigned ub = __float_as_uint(b) + 0x8000u;
    return __builtin_amdgcn_perm(ub, ua, 0x07060302u);  // lo=bf16(a), hi=bf16(b)
}

// out[b,o] = bias[o]; main kernel atomically adds K-split partials on top.
__global__ __launch_bounds__(256)
void init_out_kernel(const float* __restrict__ bias, float* __restrict__ out) {
    const int i = blockIdx.x * 256 + threadIdx.x;
    out[i] = bias[i & (OUT_F - 1)];
}

// Direct-streaming design: W never touches LDS. Each wave owns 16 out rows;
// the MFMA B-fragment (lane l -> W[o0+(l&15)][32t+(l>>4)*8+j], 32 B/lane
// contiguous, 128 B/row tiled by 4 lanes) is loaded HBM->VGPR, dequanted
// in-flight (scale hoisted per 128-K group), packed bf16, fed to MFMA.
// Only x (L2-resident) is staged in LDS, once, with a single barrier.
// grid = (OUT_F/64, KSPLIT) = (128, 8) = 1024 blocks = exactly 4/CU;
// LDS 32 KB, target 16 waves/CU.
__global__ __launch_bounds__(256, 4)
void axcore_stream_kernel(const float* __restrict__ x,
                          const float* __restrict__ w,
                          const float* __restrict__ scale,
                          float* __restrict__ out) {
    __shared__ __align__(16) unsigned short xswz[NSTEP * 64 * 8];   // 32 KB

    const int t    = threadIdx.x;
    const int wv   = t >> 6;
    const int lane = t & 63;
    const int k0   = blockIdx.y * KRANGE;
    const int ob   = blockIdx.x * 64;           // block's first out row
    const int o0   = ob + wv * 16;              // wave's first out row

    // ---- stage x[0:16][k0:k0+1024] -> bf16, A-frag swizzled ----
    // elem (m, kl): tt=kl>>5, ln=m+16*((kl&31)>>3), j=kl&7
#pragma unroll
    for (int p = 0; p < 16; ++p) {
        const int idx = p * 256 + t;            // float4 id in [0, 4096)
        const int m   = idx >> 8;               // batch
        const int k4  = (idx & 255) * 4;        // klocal
        const float4 v = *(const float4*)&x[m * IN_F + k0 + k4];
        const int tt = k4 >> 5;
        const int ln = m + 16 * ((k4 & 31) >> 3);
        const int jj = k4 & 7;                  // 0 or 4
        uint2 sv;
        sv.x = bfpack2(v.x, v.y);
        sv.y = bfpack2(v.z, v.w);
        *(uint2*)&xswz[(tt * 64 + ln) * 8 + jj] = sv;
    }
    __syncthreads();                            // the only barrier

    const int nrow = o0 + (lane & 15);          // this lane's out row (B n-index)
    const int koff = (lane >> 4) * 8;           // k-octet within 32-k step
    const float* wp = w + (size_t)nrow * IN_F + k0 + koff;
    const float* sp = scale + nrow * NG + blockIdx.y * GPB;

    f32x4 acc = {0.f, 0.f, 0.f, 0.f};

    // ---- K loop: 32 steps, 8 scale groups x 4 steps. Per step: 32 B of W
    //      per lane straight from HBM, dequant+pack in regs, 1 MFMA. ----
#pragma unroll 2
    for (int g = 0; g < GPB; ++g) {
        const float s = sp[g];                  // one scale per 4 steps
#pragma unroll
        for (int u = 0; u < 4; ++u) {
            const int ts = g * 4 + u;           // global step 0..31
            const float4 f0 = *(const float4*)(wp + ts * 32);
            const float4 f1 = *(const float4*)(wp + ts * 32 + 4);
            uint4 pk;
            pk.x = bfpack2(f0.x * s, f0.y * s);
            pk.y = bfpack2(f0.z * s, f0.w * s);
            pk.z = bfpack2(f1.x * s, f1.y * s);
            pk.w = bfpack2(f1.z * s, f1.w * s);
            union { uint4 u4; bf16x8 h; } cv;
            cv.u4 = pk;
            const bf16x8 afrag = *(const bf16x8*)&xswz[(ts * 64 + lane) * 8];
            acc = __builtin_amdgcn_mfma_f32_16x16x32_bf16(afrag, cv.h, acc, 0, 0, 0);
        }
    }

    // ---- epilogue: D[col=lane&15 -> row nrow][reg r -> batch (lane>>4)*4+r]
#pragma unroll
    for (int r = 0; r < 4; ++r) {
        const int b = (lane >> 4) * 4 + r;
        atomicAdd(&out[b * OUT_F + nrow], acc[r]);
    }
}

extern "C" void kernel_launch(void* const* d_in, const int* in_sizes, int n_in,
                              void* d_out, int out_size, void* d_ws, size_t ws_size,
                              hipStream_t stream) {
    const float* x    = (const float*)d_in[0];
    const float* w    = (const float*)d_in[1];
    const float* sc   = (const float*)d_in[2];
    const float* bias = (const float*)d_in[3];
    // d_in[4] = types: constant lookup, no float math -> unused
    float* out = (float*)d_out;

    hipLaunchKernelGGL(init_out_kernel, dim3(NB * OUT_F / 256), dim3(256),
                       0, stream, bias, out);
    hipLaunchKernelGGL(axcore_stream_kernel, dim3(OUT_F / 64, KSPLIT), dim3(256),
                       0, stream, x, w, sc, out);
}

// Round 2
// 367.250 us; speedup vs baseline: 1.0329x; 1.0329x over previous
//
#include <hip/hip_runtime.h>

#define IN_F 8192
#define OUT_F 8192
#define NB 16
#define NG 64                    // scale groups (group = 128 in-features)
#define KSPLIT 8
#define KRANGE (IN_F / KSPLIT)   // 1024 K per block
#define NSTEP (KRANGE / 32)      // 32 MFMA K-steps per block
#define GPB (KRANGE / 128)       // 8 scale groups per block

typedef __attribute__((ext_vector_type(8))) short bf16x8;
typedef __attribute__((ext_vector_type(4))) float f32x4;

// pack 2 floats -> 2 bf16 (round-half-away): 2 adds + 1 v_perm_b32
static __device__ __forceinline__ unsigned bfpack2(float a, float b) {
    unsigned ua = __float_as_uint(a) + 0x8000u;
    unsigned ub = __float_as_uint(b) + 0x8000u;
    return __builtin_amdgcn_perm(ub, ua, 0x07060302u);  // lo=bf16(a), hi=bf16(b)
}

// out[b,o] = bias[o]; main kernel atomically adds K-split partials on top.
__global__ __launch_bounds__(256)
void init_out_kernel(const float* __restrict__ bias, float* __restrict__ out) {
    const int i = blockIdx.x * 256 + threadIdx.x;
    out[i] = bias[i & (OUT_F - 1)];
}

// Direct-streaming, group-pipelined: W never touches LDS. Each wave owns 16
// out rows; the MFMA B-fragment (lane l -> W[o0+(l&15)][32t+(l>>4)*8+j],
// 32 B/lane/step contiguous) is loaded HBM->VGPR with nontemporal hint
// (read-once stream; don't evict the L2-resident x slices), dequanted in
// regs, fed to MFMA. Software pipeline at scale-group granularity: while
// group g's 4 MFMA steps compute, group g+1's 8 float4 loads are in flight
// in the other half of a double register buffer (all indices static via
// full unroll). All 8 scales hoisted before the loop.
// grid = (OUT_F/64, KSPLIT) = (128, 8) = 1024 blocks = exactly 4/CU;
// LDS 32 KB, 16 waves/CU, VGPR budget 128.
__global__ __launch_bounds__(256, 4)
void axcore_stream_kernel(const float* __restrict__ x,
                          const float* __restrict__ w,
                          const float* __restrict__ scale,
                          float* __restrict__ out) {
    __shared__ __align__(16) unsigned short xswz[NSTEP * 64 * 8];   // 32 KB

    const int t    = threadIdx.x;
    const int wv   = t >> 6;
    const int lane = t & 63;
    const int k0   = blockIdx.y * KRANGE;
    const int ob   = blockIdx.x * 64;           // block's first out row
    const int o0   = ob + wv * 16;              // wave's first out row

    // ---- stage x[0:16][k0:k0+1024] -> bf16, A-frag swizzled ----
    // elem (m, kl): tt=kl>>5, ln=m+16*((kl&31)>>3), j=kl&7
#pragma unroll
    for (int p = 0; p < 16; ++p) {
        const int idx = p * 256 + t;            // float4 id in [0, 4096)
        const int m   = idx >> 8;               // batch
        const int k4  = (idx & 255) * 4;        // klocal
        const float4 v = *(const float4*)&x[m * IN_F + k0 + k4];
        const int tt = k4 >> 5;
        const int ln = m + 16 * ((k4 & 31) >> 3);
        const int jj = k4 & 7;                  // 0 or 4
        uint2 sv;
        sv.x = bfpack2(v.x, v.y);
        sv.y = bfpack2(v.z, v.w);
        *(uint2*)&xswz[(tt * 64 + ln) * 8 + jj] = sv;
    }
    __syncthreads();                            // the only barrier

    const int nrow = o0 + (lane & 15);          // this lane's out row (B n-index)
    const int koff = (lane >> 4) * 8;           // k-octet within 32-k step
    const float* wp = w + (size_t)nrow * IN_F + k0 + koff;
    const float* sp = scale + nrow * NG + blockIdx.y * GPB;

    // hoist all 8 group scales (latency fully off the critical path)
    float sreg[GPB];
#pragma unroll
    for (int g = 0; g < GPB; ++g) sreg[g] = sp[g];

    f32x4 acc = {0.f, 0.f, 0.f, 0.f};
    f32x4 wbuf[2][8];                           // [phase][2 float4 x 4 steps]

    // prologue: load group 0
#pragma unroll
    for (int u = 0; u < 4; ++u) {
        wbuf[0][2 * u]     = __builtin_nontemporal_load((const f32x4*)(wp + u * 32));
        wbuf[0][2 * u + 1] = __builtin_nontemporal_load((const f32x4*)(wp + u * 32 + 4));
    }

    // ---- K loop: 8 scale groups x 4 MFMA steps, double-buffered in regs ----
#pragma unroll
    for (int g = 0; g < GPB; ++g) {
        const int cur = g & 1;                  // compile-time (full unroll)
        if (g + 1 < GPB) {
#pragma unroll
            for (int u = 0; u < 4; ++u) {
                const int ts = (g + 1) * 4 + u;
                wbuf[cur ^ 1][2 * u]     = __builtin_nontemporal_load((const f32x4*)(wp + ts * 32));
                wbuf[cur ^ 1][2 * u + 1] = __builtin_nontemporal_load((const f32x4*)(wp + ts * 32 + 4));
            }
        }
        const float s = sreg[g];
#pragma unroll
        for (int u = 0; u < 4; ++u) {
            const int ts = g * 4 + u;           // global step 0..31
            const f32x4 f0 = wbuf[cur][2 * u];
            const f32x4 f1 = wbuf[cur][2 * u + 1];
            uint4 pk;
            pk.x = bfpack2(f0.x * s, f0.y * s);
            pk.y = bfpack2(f0.z * s, f0.w * s);
            pk.z = bfpack2(f1.x * s, f1.y * s);
            pk.w = bfpack2(f1.z * s, f1.w * s);
            union { uint4 u4; bf16x8 h; } cv;
            cv.u4 = pk;
            const bf16x8 afrag = *(const bf16x8*)&xswz[(ts * 64 + lane) * 8];
            acc = __builtin_amdgcn_mfma_f32_16x16x32_bf16(afrag, cv.h, acc, 0, 0, 0);
        }
    }

    // ---- epilogue: D[col=lane&15 -> row nrow][reg r -> batch (lane>>4)*4+r]
#pragma unroll
    for (int r = 0; r < 4; ++r) {
        const int b = (lane >> 4) * 4 + r;
        atomicAdd(&out[b * OUT_F + nrow], acc[r]);
    }
}

extern "C" void kernel_launch(void* const* d_in, const int* in_sizes, int n_in,
                              void* d_out, int out_size, void* d_ws, size_t ws_size,
                              hipStream_t stream) {
    const float* x    = (const float*)d_in[0];
    const float* w    = (const float*)d_in[1];
    const float* sc   = (const float*)d_in[2];
    const float* bias = (const float*)d_in[3];
    // d_in[4] = types: constant lookup, no float math -> unused
    float* out = (float*)d_out;

    hipLaunchKernelGGL(init_out_kernel, dim3(NB * OUT_F / 256), dim3(256),
                       0, stream, bias, out);
    hipLaunchKernelGGL(axcore_stream_kernel, dim3(OUT_F / 64, KSPLIT), dim3(256),
                       0, stream, x, w, sc, out);
}